// Round 11
// baseline (195.452 us; speedup 1.0000x reference)
//
#include <hip/hip_runtime.h>
#include <math.h>

#define BS 8192
#define HALF 4096
#define DIM 1024
#define BIGP 1.0e10f
#define SQRT_TAU_INV 4.472135955f  // sqrt(20): prescale both operands -> acc = sim/tau

typedef __attribute__((ext_vector_type(8))) short bf16x8;
typedef __attribute__((ext_vector_type(4))) float f32x4;

#define GLOAD_LDS16(g, l)                                              \
    __builtin_amdgcn_global_load_lds(                                  \
        (const __attribute__((address_space(1))) void*)(g),            \
        (__attribute__((address_space(3))) void*)(l), 16, 0, 0)

__device__ inline unsigned short f2bf(float f) {
    union { float f; unsigned int u; } c; c.f = f;
    unsigned int u = c.u;
    u += 0x7FFFu + ((u >> 16) & 1u);
    return (unsigned short)(u >> 16);
}

// ---------------------------------------------------------------------------
// 1) Row-normalize concat(f1,f2), scale by sqrt(1/tau), convert to bf16.
// ---------------------------------------------------------------------------
__global__ __launch_bounds__(256) void norm_kernel(const float* __restrict__ f1,
                                                   const float* __restrict__ f2,
                                                   unsigned short* __restrict__ nb) {
    const int row = blockIdx.x;
    const int t = threadIdx.x;
    const float* src = (row < HALF) ? (f1 + (size_t)row * DIM)
                                    : (f2 + (size_t)(row - HALF) * DIM);
    float4 v = reinterpret_cast<const float4*>(src)[t];
    float ss = v.x * v.x + v.y * v.y + v.z * v.z + v.w * v.w;
#pragma unroll
    for (int off = 32; off > 0; off >>= 1) ss += __shfl_down(ss, off, 64);
    __shared__ float red[4];
    if ((t & 63) == 0) red[t >> 6] = ss;
    __syncthreads();
    float tot = red[0] + red[1] + red[2] + red[3];
    float inv = SQRT_TAU_INV / fmaxf(sqrtf(tot), 1e-8f);
    ushort4 o;
    o.x = f2bf(v.x * inv);
    o.y = f2bf(v.y * inv);
    o.z = f2bf(v.z * inv);
    o.w = f2bf(v.w * inv);
    reinterpret_cast<ushort4*>(nb + (size_t)row * DIM)[t] = o;
}

// ---------------------------------------------------------------------------
// 2) SYMMETRIC S/tau = N'*N'^T, upper-triangle blocks, XCD-PINNED ordering
//    (round-8 decode, round-10 epilogue): grid = 64 cols x 64 slots; slot
//    s -> class x = s%8 = id%8 (-> XCD x), occurrence o = s>>3 -> row by;
//    real iff by <= bx (dummies exit). Class x owns rows {x,15-x,16+x,31-x,
//    ...}: its 8 A-panels (2 MB) stay L2-resident on its XCD; all XCDs sweep
//    the same B-column together (columns descend for a smooth tail).
//    K-loop: m97 structure (global_load_lds w16, both-sides XOR swizzle).
//    Epilogue: barrier-free; direct scalar stores + register-direct
//    transposed f32x4 stores + per-wave LSE partials straight to 128-slot
//    psum (row-sums -> slot 2bx+wc, col-sums -> slot 2by+wr; unique writer
//    per (slot,row)). LDS exactly 32 KB.
// ---------------------------------------------------------------------------
#define BM 128
#define BN 128
#define BK 64

__global__ __launch_bounds__(256) void gemm_kernel(const unsigned short* __restrict__ nb,
                                                   float* __restrict__ logits,
                                                   float* __restrict__ psum,
                                                   float* __restrict__ targ) {
    // XCD-pinned triangular decode
    const int id = blockIdx.x;
    const int bx = 63 - (id >> 6);          // column, descending
    const int s = id & 63;
    const int x = s & 7;                    // class == id%8 (XCD)
    const int o = s >> 3;                   // occurrence within class
    const int by = (o & 1) ? ((((o + 1) >> 1) << 4) - 1 - x)
                           : (((o >> 1) << 4) + x);
    if (by > bx) return;                    // dummy slot
    const bool diag = (bx == by);

    __shared__ unsigned short As[BM][BK];   // 16 KB
    __shared__ unsigned short Bs[BN][BK];   // 16 KB  (total exactly 32 KB)

    const int t = threadIdx.x;
    const int lane = t & 63;
    const int wid = t >> 6;
    const int wr = wid >> 1;
    const int wc = wid & 1;
    const int lo = lane & 15;
    const int hi = lane >> 4;

    const int rowBase = by * BM;
    const int colBase = bx * BN;

    f32x4 acc[4][4];
#pragma unroll
    for (int m = 0; m < 4; ++m)
#pragma unroll
        for (int n = 0; n < 4; ++n) {
            acc[m][n][0] = 0.f; acc[m][n][1] = 0.f;
            acc[m][n][2] = 0.f; acc[m][n][3] = 0.f;
        }

    // staging: LDS(row, cb) holds global (row, cb ^ ((row&7)<<4)) [bytes]
    const int srow = lane >> 3;
    const int skoff = (((lane & 7) ^ srow) << 3);
    const char* Abase = (const char*)&As[0][0];
    const char* Bbase = (const char*)&Bs[0][0];
    const int rswz = (lo & 7) << 4;

    for (int kt = 0; kt < DIM; kt += BK) {
#pragma unroll
        for (int i = 0; i < 4; ++i) {
            const int chunk = wid * 4 + i;
            const int r = chunk * 8 + srow;
            const unsigned short* gA = nb + (size_t)(rowBase + r) * DIM + kt + skoff;
            GLOAD_LDS16(gA, (char*)&As[0][0] + chunk * 1024);
            const unsigned short* gB = nb + (size_t)(colBase + r) * DIM + kt + skoff;
            GLOAD_LDS16(gB, (char*)&Bs[0][0] + chunk * 1024);
        }
        __syncthreads();

#pragma unroll
        for (int ks = 0; ks < BK; ks += 32) {
            bf16x8 a[4], b[4];
#pragma unroll
            for (int m = 0; m < 4; ++m) {
                const int rr = wr * 64 + m * 16 + lo;
                a[m] = *reinterpret_cast<const bf16x8*>(
                    Abase + rr * 128 + ((ks * 2 + hi * 16) ^ rswz));
            }
#pragma unroll
            for (int n = 0; n < 4; ++n) {
                const int rr = wc * 64 + n * 16 + lo;
                b[n] = *reinterpret_cast<const bf16x8*>(
                    Bbase + rr * 128 + ((ks * 2 + hi * 16) ^ rswz));
            }
#pragma unroll
            for (int m = 0; m < 4; ++m)
#pragma unroll
                for (int n = 0; n < 4; ++n)
                    acc[m][n] = __builtin_amdgcn_mfma_f32_16x16x32_bf16(a[m], b[n], acc[m][n], 0, 0, 0);
        }
        __syncthreads();
    }

    // ---- diagonal mask in place (diag blocks only: rowBase==colBase) ----
    if (diag) {
#pragma unroll
        for (int m = 0; m < 4; ++m) {
            const int lr0 = wr * 64 + m * 16 + hi * 4;
#pragma unroll
            for (int n = 0; n < 4; ++n) {
                const int lc = wc * 64 + n * 16 + lo;
#pragma unroll
                for (int r = 0; r < 4; ++r)
                    if (lr0 + r == lc) acc[m][n][r] -= BIGP;
            }
        }
    }

    // ---- pass 1: direct scalar stores + exp row/col partials + targets ----
    // C/D mapping: col = lane&15 (+n*16), row = (lane>>4)*4 + reg (+m*16).
    float sums[16];
    float psn[4] = {0.f, 0.f, 0.f, 0.f};
#pragma unroll
    for (int p = 0; p < 16; ++p) sums[p] = 0.f;

#pragma unroll
    for (int m = 0; m < 4; ++m) {
        const int trow0 = rowBase + wr * 64 + m * 16 + hi * 4;
#pragma unroll
        for (int n = 0; n < 4; ++n) {
            const int col = colBase + wc * 64 + n * 16 + lo;
#pragma unroll
            for (int r = 0; r < 4; ++r) {
                const int row = trow0 + r;
                const float v = acc[m][n][r];
                logits[(size_t)row * BS + col] = v;
                if (col == row + HALF) { targ[row] = v; targ[col] = v; }
                const float e = __expf(v - 20.0f);  // diag cell -> 0
                sums[m * 4 + r] += e;
                psn[n] += e;
            }
        }
    }

    // ---- pass 2: transposed tile, register-direct f32x4 stores ----
    if (!diag) {
#pragma unroll
        for (int m = 0; m < 4; ++m) {
            const int trow0 = rowBase + wr * 64 + m * 16 + hi * 4;
#pragma unroll
            for (int n = 0; n < 4; ++n) {
                const int col = colBase + wc * 64 + n * 16 + lo;
                *reinterpret_cast<f32x4*>(&logits[(size_t)col * BS + trow0]) = acc[m][n];
            }
        }
    }

    // ---- row-sum reduce across the 16-lane col group; write slot 2bx+wc ----
    float sel = 0.f;
#pragma unroll
    for (int p = 0; p < 16; ++p) {
        float sv = sums[p];
        sv += __shfl_xor(sv, 1, 64);
        sv += __shfl_xor(sv, 2, 64);
        sv += __shfl_xor(sv, 4, 64);
        sv += __shfl_xor(sv, 8, 64);
        sel = (lo == p) ? sv : sel;
    }
    // lane (hi*16+lo) holds row-sum for local row wr*64 + (lo>>2)*16 + hi*4 + (lo&3)
    psum[(size_t)(2 * bx + wc) * BS + rowBase + wr * 64 + (lo >> 2) * 16 + hi * 4 + (lo & 3)] = sel;

    // ---- col-sum reduce over hi groups; write slot 2by+wr (non-diag) ----
    if (!diag) {
#pragma unroll
        for (int n = 0; n < 4; ++n) {
            psn[n] += __shfl_xor(psn[n], 16, 64);
            psn[n] += __shfl_xor(psn[n], 32, 64);
        }
        const float cw = (hi == 0) ? psn[0] : (hi == 1) ? psn[1]
                       : (hi == 2) ? psn[2] : psn[3];
        psum[(size_t)(2 * by + wr) * BS + colBase + wc * 64 + hi * 16 + lo] = cw;
    }
}

// ---------------------------------------------------------------------------
// 3) Per-row: total = sum over 128 psum slots, pe = -(targ - 20 - log total);
//    block partials of w*pe and w; also writes y_true (f32). 32 blocks x 256.
// ---------------------------------------------------------------------------
__global__ __launch_bounds__(256) void reduce_rows_kernel(const float* __restrict__ psum,
                                                          const float* __restrict__ targ,
                                                          const int* __restrict__ mask,
                                                          float* __restrict__ partials,
                                                          float* __restrict__ ytrue_out) {
    const int t = threadIdx.x;
    const int row = blockIdx.x * 256 + t;

    float total = 0.f;
#pragma unroll 8
    for (int cb = 0; cb < 128; ++cb) total += psum[(size_t)cb * BS + row];

    const float pe = -(targ[row] - 20.0f - logf(total));
    const float w = 1.0f - (float)mask[row & (HALF - 1)];
    ytrue_out[row] = (float)((row < HALF) ? row + HALF : row - HALF);

    float a = w * pe, b = w;
#pragma unroll
    for (int off = 32; off > 0; off >>= 1) {
        a += __shfl_down(a, off, 64);
        b += __shfl_down(b, off, 64);
    }
    __shared__ float ra[4], rb[4];
    if ((t & 63) == 0) { ra[t >> 6] = a; rb[t >> 6] = b; }
    __syncthreads();
    if (t == 0) {
        partials[blockIdx.x] = ra[0] + ra[1] + ra[2] + ra[3];
        partials[32 + blockIdx.x] = rb[0] + rb[1] + rb[2] + rb[3];
    }
}

__global__ void loss_kernel(const float* __restrict__ partials,
                            float* __restrict__ loss_out) {
    if (threadIdx.x == 0) {
        float A = 0.f, B = 0.f;
        for (int i = 0; i < 32; ++i) { A += partials[i]; B += partials[32 + i]; }
        loss_out[0] = A / B;
    }
}

// ---------------------------------------------------------------------------
extern "C" void kernel_launch(void* const* d_in, const int* in_sizes, int n_in,
                              void* d_out, int out_size, void* d_ws, size_t ws_size,
                              hipStream_t stream) {
    const float* f1 = (const float*)d_in[0];
    const float* f2 = (const float*)d_in[1];
    const int* mask = (const int*)d_in[2];
    float* out = (float*)d_out;

    unsigned short* nb = (unsigned short*)d_ws;                          // 16 MB
    float* psum = (float*)((char*)d_ws + (size_t)BS * DIM * 2);          // 4 MB (128 x 8192)
    float* targ = psum + (size_t)128 * BS;                               // 32 KB
    float* partials = targ + BS;                                         // 256 B
    float* logits = out + 1;
    float* ytrue_out = out + 1 + (size_t)BS * BS;

    norm_kernel<<<BS, 256, 0, stream>>>(f1, f2, nb);

    gemm_kernel<<<64 * 64, 256, 0, stream>>>(nb, logits, psum, targ);

    reduce_rows_kernel<<<BS / 256, 256, 0, stream>>>(psum, targ, mask, partials, ytrue_out);
    loss_kernel<<<1, 64, 0, stream>>>(partials, out);
}

// Round 12
// 171.948 us; speedup vs baseline: 1.1367x; 1.1367x over previous
//
#include <hip/hip_runtime.h>
#include <math.h>

#define BS 8192
#define HALF 4096
#define DIM 1024
#define BIGP 1.0e10f
#define SQRT_TAU_INV 4.472135955f  // sqrt(20): prescale both operands -> acc = sim/tau

typedef __attribute__((ext_vector_type(8))) short bf16x8;
typedef __attribute__((ext_vector_type(4))) float f32x4;

#define GLOAD_LDS16(g, l)                                              \
    __builtin_amdgcn_global_load_lds(                                  \
        (const __attribute__((address_space(1))) void*)(g),            \
        (__attribute__((address_space(3))) void*)(l), 16, 0, 0)

__device__ inline unsigned short f2bf(float f) {
    union { float f; unsigned int u; } c; c.f = f;
    unsigned int u = c.u;
    u += 0x7FFFu + ((u >> 16) & 1u);
    return (unsigned short)(u >> 16);
}

// ---------------------------------------------------------------------------
// 1) Row-normalize concat(f1,f2), scale by sqrt(1/tau), convert to bf16.
// ---------------------------------------------------------------------------
__global__ __launch_bounds__(256) void norm_kernel(const float* __restrict__ f1,
                                                   const float* __restrict__ f2,
                                                   unsigned short* __restrict__ nb) {
    const int row = blockIdx.x;
    const int t = threadIdx.x;
    const float* src = (row < HALF) ? (f1 + (size_t)row * DIM)
                                    : (f2 + (size_t)(row - HALF) * DIM);
    float4 v = reinterpret_cast<const float4*>(src)[t];
    float ss = v.x * v.x + v.y * v.y + v.z * v.z + v.w * v.w;
#pragma unroll
    for (int off = 32; off > 0; off >>= 1) ss += __shfl_down(ss, off, 64);
    __shared__ float red[4];
    if ((t & 63) == 0) red[t >> 6] = ss;
    __syncthreads();
    float tot = red[0] + red[1] + red[2] + red[3];
    float inv = SQRT_TAU_INV / fmaxf(sqrtf(tot), 1e-8f);
    ushort4 o;
    o.x = f2bf(v.x * inv);
    o.y = f2bf(v.y * inv);
    o.z = f2bf(v.z * inv);
    o.w = f2bf(v.w * inv);
    reinterpret_cast<ushort4*>(nb + (size_t)row * DIM)[t] = o;
}

// ---------------------------------------------------------------------------
// 2) SYMMETRIC S/tau = N'*N'^T, upper-triangle blocks, column-major order
//    (round-10 structure). K-loop: m97 (global_load_lds w16, both-sides XOR
//    swizzle). Epilogue: ALL-VECTOR stores, barrier-free:
//      a) diag mask in place;
//      b) transposed-tile f32x4 stores from acc (issued first, non-diag);
//      c) col-sum partials from acc -> psum slot 2*by+wr (non-diag);
//      d) in-register 4x4 lane transpose (round-9-verified) -> direct f32x4
//         stores + exp row-sums + target extract -> psum slot 2*bx+wc.
//    NO min-waves launch_bounds cap (round-9 lesson: the cap forced a spill,
//    VGPR 48 + ~700 MB scratch traffic).
// ---------------------------------------------------------------------------
#define BM 128
#define BN 128
#define BK 64

__global__ __launch_bounds__(256) void gemm_kernel(const unsigned short* __restrict__ nb,
                                                   float* __restrict__ logits,
                                                   float* __restrict__ psum,
                                                   float* __restrict__ targ) {
    __shared__ unsigned short As[BM][BK];   // 16 KB
    __shared__ unsigned short Bs[BN][BK];   // 16 KB  (total exactly 32 KB)

    const int t = threadIdx.x;
    const int lane = t & 63;
    const int wid = t >> 6;
    const int wr = wid >> 1;
    const int wc = wid & 1;
    const int lo = lane & 15;
    const int hi = lane >> 4;

    // triangular decode: column-major upper triangle, bx >= by
    const int id = blockIdx.x;
    int bx = (int)((sqrtf(8.0f * (float)id + 1.0f) - 1.0f) * 0.5f);
    while ((bx + 1) * (bx + 2) / 2 <= id) ++bx;
    while (bx * (bx + 1) / 2 > id) --bx;
    const int by = id - bx * (bx + 1) / 2;
    const bool diag = (bx == by);

    const int rowBase = by * BM;
    const int colBase = bx * BN;

    f32x4 acc[4][4];
#pragma unroll
    for (int m = 0; m < 4; ++m)
#pragma unroll
        for (int n = 0; n < 4; ++n) {
            acc[m][n][0] = 0.f; acc[m][n][1] = 0.f;
            acc[m][n][2] = 0.f; acc[m][n][3] = 0.f;
        }

    // staging: LDS(row, cb) holds global (row, cb ^ ((row&7)<<4)) [bytes]
    const int srow = lane >> 3;
    const int skoff = (((lane & 7) ^ srow) << 3);
    const char* Abase = (const char*)&As[0][0];
    const char* Bbase = (const char*)&Bs[0][0];
    const int rswz = (lo & 7) << 4;

    for (int kt = 0; kt < DIM; kt += BK) {
#pragma unroll
        for (int i = 0; i < 4; ++i) {
            const int chunk = wid * 4 + i;
            const int r = chunk * 8 + srow;
            const unsigned short* gA = nb + (size_t)(rowBase + r) * DIM + kt + skoff;
            GLOAD_LDS16(gA, (char*)&As[0][0] + chunk * 1024);
            const unsigned short* gB = nb + (size_t)(colBase + r) * DIM + kt + skoff;
            GLOAD_LDS16(gB, (char*)&Bs[0][0] + chunk * 1024);
        }
        __syncthreads();

#pragma unroll
        for (int ks = 0; ks < BK; ks += 32) {
            bf16x8 a[4], b[4];
#pragma unroll
            for (int m = 0; m < 4; ++m) {
                const int rr = wr * 64 + m * 16 + lo;
                a[m] = *reinterpret_cast<const bf16x8*>(
                    Abase + rr * 128 + ((ks * 2 + hi * 16) ^ rswz));
            }
#pragma unroll
            for (int n = 0; n < 4; ++n) {
                const int rr = wc * 64 + n * 16 + lo;
                b[n] = *reinterpret_cast<const bf16x8*>(
                    Bbase + rr * 128 + ((ks * 2 + hi * 16) ^ rswz));
            }
#pragma unroll
            for (int m = 0; m < 4; ++m)
#pragma unroll
                for (int n = 0; n < 4; ++n)
                    acc[m][n] = __builtin_amdgcn_mfma_f32_16x16x32_bf16(a[m], b[n], acc[m][n], 0, 0, 0);
        }
        __syncthreads();
    }

    // ---- a) diagonal mask in place ----
    if (diag) {
#pragma unroll
        for (int m = 0; m < 4; ++m) {
            const int lr0 = wr * 64 + m * 16 + hi * 4;
#pragma unroll
            for (int n = 0; n < 4; ++n) {
                const int lc = wc * 64 + n * 16 + lo;
#pragma unroll
                for (int r = 0; r < 4; ++r)
                    if (lr0 + r == lc) acc[m][n][r] -= BIGP;
            }
        }
    }

    // ---- b) transposed-tile f32x4 stores from acc (issue early) ----
    if (!diag) {
#pragma unroll
        for (int m = 0; m < 4; ++m) {
            const int trow0 = rowBase + wr * 64 + m * 16 + hi * 4;
#pragma unroll
            for (int n = 0; n < 4; ++n) {
                const int col = colBase + wc * 64 + n * 16 + lo;
                *reinterpret_cast<f32x4*>(&logits[(size_t)col * BS + trow0]) = acc[m][n];
            }
        }
    }

    // ---- c) col-sum partials from acc -> slot 2*by+wr (non-diag) ----
    {
        float psn[4] = {0.f, 0.f, 0.f, 0.f};
#pragma unroll
        for (int m = 0; m < 4; ++m)
#pragma unroll
            for (int n = 0; n < 4; ++n)
#pragma unroll
                for (int r = 0; r < 4; ++r)
                    psn[n] += __expf(acc[m][n][r] - 20.0f);   // diag cell -> 0
        if (!diag) {
#pragma unroll
            for (int n = 0; n < 4; ++n) {
                psn[n] += __shfl_xor(psn[n], 16, 64);
                psn[n] += __shfl_xor(psn[n], 32, 64);
            }
            const float cw = (hi == 0) ? psn[0] : (hi == 1) ? psn[1]
                           : (hi == 2) ? psn[2] : psn[3];
            psum[(size_t)(2 * by + wr) * BS + colBase + wc * 64 + hi * 16 + lo] = cw;
        }
    }

    // ---- d) in-register 4x4 transpose -> direct f32x4 stores + row-sums ----
    const int p = lane & 3;        // position within 4-lane transpose group
    const int g = (lane >> 2) & 3; // which 4-col group
    float rsum[4] = {0.f, 0.f, 0.f, 0.f};
#pragma unroll
    for (int m = 0; m < 4; ++m) {
        const int row = rowBase + wr * 64 + m * 16 + hi * 4 + p;
#pragma unroll
        for (int n = 0; n < 4; ++n) {
            const float t0 = acc[m][n][0], t1 = acc[m][n][1];
            const float t2 = acc[m][n][2], t3 = acc[m][n][3];
            // stage 1 (lane bit 0)
            const float s0 = __shfl_xor(t1, 1, 64);
            const float s1 = __shfl_xor(t0, 1, 64);
            const float s2 = __shfl_xor(t3, 1, 64);
            const float s3 = __shfl_xor(t2, 1, 64);
            const float a0 = (p & 1) ? s0 : t0;
            const float a1 = (p & 1) ? t1 : s1;
            const float a2 = (p & 1) ? s2 : t2;
            const float a3 = (p & 1) ? t3 : s3;
            // stage 2 (lane bit 1)
            const float u0 = __shfl_xor(a2, 2, 64);
            const float u1 = __shfl_xor(a3, 2, 64);
            const float u2 = __shfl_xor(a0, 2, 64);
            const float u3 = __shfl_xor(a1, 2, 64);
            f32x4 w;
            w[0] = (p & 2) ? u0 : a0;
            w[1] = (p & 2) ? u1 : a1;
            w[2] = (p & 2) ? a2 : u2;
            w[3] = (p & 2) ? a3 : u3;
            // lane p holds row `row`, cols cb0..cb0+3
            const int cb0 = colBase + wc * 64 + n * 16 + 4 * g;
            *reinterpret_cast<f32x4*>(&logits[(size_t)row * BS + cb0]) = w;
#pragma unroll
            for (int q = 0; q < 4; ++q) {
                rsum[m] += __expf(w[q] - 20.0f);
                if (cb0 + q == row + HALF) { targ[row] = w[q]; targ[row + HALF] = w[q]; }
            }
        }
    }
    // reduce row-sums over the 4 col-groups (lane bits 2,3), pick m==g
#pragma unroll
    for (int m = 0; m < 4; ++m) {
        rsum[m] += __shfl_xor(rsum[m], 4, 64);
        rsum[m] += __shfl_xor(rsum[m], 8, 64);
    }
    const float rw = (g == 0) ? rsum[0] : (g == 1) ? rsum[1]
                   : (g == 2) ? rsum[2] : rsum[3];
    psum[(size_t)(2 * bx + wc) * BS + rowBase + wr * 64 + g * 16 + hi * 4 + p] = rw;
}

// ---------------------------------------------------------------------------
// 3) Per-row: total = sum over 128 psum slots, pe = -(targ - 20 - log total);
//    block partials of w*pe and w; also writes y_true (f32). 32 blocks x 256.
// ---------------------------------------------------------------------------
__global__ __launch_bounds__(256) void reduce_rows_kernel(const float* __restrict__ psum,
                                                          const float* __restrict__ targ,
                                                          const int* __restrict__ mask,
                                                          float* __restrict__ partials,
                                                          float* __restrict__ ytrue_out) {
    const int t = threadIdx.x;
    const int row = blockIdx.x * 256 + t;

    float total = 0.f;
#pragma unroll 8
    for (int cb = 0; cb < 128; ++cb) total += psum[(size_t)cb * BS + row];

    const float pe = -(targ[row] - 20.0f - logf(total));
    const float w = 1.0f - (float)mask[row & (HALF - 1)];
    ytrue_out[row] = (float)((row < HALF) ? row + HALF : row - HALF);

    float a = w * pe, b = w;
#pragma unroll
    for (int off = 32; off > 0; off >>= 1) {
        a += __shfl_down(a, off, 64);
        b += __shfl_down(b, off, 64);
    }
    __shared__ float ra[4], rb[4];
    if ((t & 63) == 0) { ra[t >> 6] = a; rb[t >> 6] = b; }
    __syncthreads();
    if (t == 0) {
        partials[blockIdx.x] = ra[0] + ra[1] + ra[2] + ra[3];
        partials[32 + blockIdx.x] = rb[0] + rb[1] + rb[2] + rb[3];
    }
}

__global__ void loss_kernel(const float* __restrict__ partials,
                            float* __restrict__ loss_out) {
    if (threadIdx.x == 0) {
        float A = 0.f, B = 0.f;
        for (int i = 0; i < 32; ++i) { A += partials[i]; B += partials[32 + i]; }
        loss_out[0] = A / B;
    }
}

// ---------------------------------------------------------------------------
extern "C" void kernel_launch(void* const* d_in, const int* in_sizes, int n_in,
                              void* d_out, int out_size, void* d_ws, size_t ws_size,
                              hipStream_t stream) {
    const float* f1 = (const float*)d_in[0];
    const float* f2 = (const float*)d_in[1];
    const int* mask = (const int*)d_in[2];
    float* out = (float*)d_out;

    unsigned short* nb = (unsigned short*)d_ws;                          // 16 MB
    float* psum = (float*)((char*)d_ws + (size_t)BS * DIM * 2);          // 4 MB (128 x 8192)
    float* targ = psum + (size_t)128 * BS;                               // 32 KB
    float* partials = targ + BS;                                         // 256 B
    float* logits = out + 1;
    float* ytrue_out = out + 1 + (size_t)BS * BS;

    norm_kernel<<<BS, 256, 0, stream>>>(f1, f2, nb);

    const int ntri = (BS / BM) * (BS / BM + 1) / 2;   // 2080
    gemm_kernel<<<ntri, 256, 0, stream>>>(nb, logits, psum, targ);

    reduce_rows_kernel<<<BS / 256, 256, 0, stream>>>(psum, targ, mask, partials, ytrue_out);
    loss_kernel<<<1, 64, 0, stream>>>(partials, out);
}